// Round 2
// baseline (684.182 us; speedup 1.0000x reference)
//
#include <hip/hip_runtime.h>

typedef _Float16 half8_t __attribute__((ext_vector_type(8)));
typedef _Float16 half4_t __attribute__((ext_vector_type(4)));
typedef float    f32x4   __attribute__((ext_vector_type(4)));

#define LSEQ    2048
#define DIM     64
#define ROWS    16
#define TOPK    64
#define CAP     128
#define NROWTOT 65536   // B*H*L = 2*16*2048

// ---------------- fp32 -> fp16 conversion prepass ----------------
__global__ void cvt_f16_kernel(const float* __restrict__ Q, const float* __restrict__ K,
                               _Float16* __restrict__ Q16, _Float16* __restrict__ K16, int n4)
{
    int i = blockIdx.x * blockDim.x + threadIdx.x;
    if (i >= n4) return;
    float4 q = reinterpret_cast<const float4*>(Q)[i];
    float4 k = reinterpret_cast<const float4*>(K)[i];
    half4_t hq = { (_Float16)q.x, (_Float16)q.y, (_Float16)q.z, (_Float16)q.w };
    half4_t hk = { (_Float16)k.x, (_Float16)k.y, (_Float16)k.z, (_Float16)k.w };
    reinterpret_cast<half4_t*>(Q16)[i] = hq;
    reinterpret_cast<half4_t*>(K16)[i] = hk;
}

// ---------------- main: scores (f16 MFMA) + exact top-k + PV ----------------
template <bool PRE>
__global__ __launch_bounds__(512, 4) void topk_attn_kernel(
    const float* __restrict__ Qf, const float* __restrict__ Kf, const float* __restrict__ Vf,
    const _Float16* __restrict__ Q16, const _Float16* __restrict__ K16,
    float* __restrict__ Out)
{
    __shared__ _Float16 sc[ROWS][LSEQ];     // 64 KB fp16 scores
    __shared__ float    qlds[ROWS][DIM];    // 4 KB exact Q
    __shared__ int      candIdx[8][CAP + 1];
    __shared__ int      pvK[8][TOPK];
    __shared__ float    pvW[8][TOPK];

    const int tid  = threadIdx.x;
    const int wave = tid >> 6;
    const int lane = tid & 63;

    const long rowbase  = (long)blockIdx.x * ROWS;       // global query-row base
    const long headbase = (rowbase >> 11) << 11;         // first row of this (b,h) head

    // stage exact fp32 Q rows for candidate recompute
    for (int i = tid; i < ROWS * DIM; i += 512)
        qlds[i >> 6][i & 63] = Qf[rowbase * DIM + i];

    // ---- Phase 1: fp16 scores via MFMA, direct global->fragment loads ----
    const int g = lane >> 4;     // k-chunk selector
    const int r = lane & 15;     // row (A) / col (B) within 16x16 tile

    half8_t a0, a1;
    if constexpr (PRE) {
        a0 = *reinterpret_cast<const half8_t*>(Q16 + (rowbase + r) * DIM + g * 8);
        a1 = *reinterpret_cast<const half8_t*>(Q16 + (rowbase + r) * DIM + 32 + g * 8);
    } else {
        const float* qp = Qf + (rowbase + r) * DIM + g * 8;
        #pragma unroll
        for (int j = 0; j < 8; ++j) { a0[j] = (_Float16)qp[j]; a1[j] = (_Float16)qp[32 + j]; }
    }

    #pragma unroll 4
    for (int t = 0; t < 16; ++t) {
        const int key = t * 128 + wave * 16 + r;
        half8_t b0, b1;
        if constexpr (PRE) {
            const _Float16* kp = K16 + (headbase + key) * DIM + g * 8;
            b0 = *reinterpret_cast<const half8_t*>(kp);
            b1 = *reinterpret_cast<const half8_t*>(kp + 32);
        } else {
            const float* kp = Kf + (headbase + key) * DIM + g * 8;
            #pragma unroll
            for (int j = 0; j < 8; ++j) { b0[j] = (_Float16)kp[j]; b1[j] = (_Float16)kp[32 + j]; }
        }
        f32x4 acc = {0.f, 0.f, 0.f, 0.f};
        acc = __builtin_amdgcn_mfma_f32_16x16x32_f16(a0, b0, acc, 0, 0, 0);
        acc = __builtin_amdgcn_mfma_f32_16x16x32_f16(a1, b1, acc, 0, 0, 0);
        #pragma unroll
        for (int j = 0; j < 4; ++j)
            sc[g * 4 + j][key] = (_Float16)acc[j];   // C: col=lane&15, row=(lane>>4)*4+j
    }
    __syncthreads();

    // ---- Phase 2: per-wave exact top-64 + softmax + PV (2 rows/wave) ----
    const unsigned long long mlt = (1ull << lane) - 1ull;

    for (int rr = 0; rr < 2; ++rr) {
        const int row = wave * 2 + rr;

        // 32 contiguous fp16 scores per lane (vectorized LDS reads)
        const half8_t* sp = reinterpret_cast<const half8_t*>(&sc[row][lane * 32]);
        half8_t h0 = sp[0], h1 = sp[1], h2 = sp[2], h3 = sp[3];
        float v[32];
        #pragma unroll
        for (int j = 0; j < 8; ++j) {
            v[j]      = (float)h0[j];
            v[8 + j]  = (float)h1[j];
            v[16 + j] = (float)h2[j];
            v[24 + j] = (float)h3[j];
        }

        // row statistics for threshold guess
        float sm = 0.f, s2 = 0.f;
        #pragma unroll
        for (int j = 0; j < 32; ++j) {
            sm += v[j];
            s2 = fmaf(v[j], v[j], s2);
        }
        #pragma unroll
        for (int o = 32; o > 0; o >>= 1) {
            sm += __shfl_xor(sm, o);
            s2 += __shfl_xor(s2, o);
        }
        const float mu  = sm * (1.f / LSEQ);
        const float sig = sqrtf(fmaxf(s2 * (1.f / LSEQ) - mu * mu, 0.f));

        // adaptive threshold: guarantee count(> T0+2e) >= 64 (containment) and
        // count(>= T0) <= CAP (capacity).  Bounded iteration count.
        const float E2 = 0.30f;   // 2 * conservative fp16-score error bound
        float T0  = mu + 1.60f * sig;
        float stp = 0.5f * sig + 0.05f;
        for (int it = 0; it < 16; ++it) {
            int ca = 0, ch = 0;
            #pragma unroll
            for (int j = 0; j < 32; ++j) {
                ca += (v[j] >= T0);
                ch += (v[j] > T0 + E2);
            }
            #pragma unroll
            for (int o = 32; o > 0; o >>= 1) {
                ca += __shfl_xor(ca, o);
                ch += __shfl_xor(ch, o);
            }
            if (ch >= TOPK && ca <= CAP) break;
            T0 += (ca > CAP) ? stp : -stp;
            stp *= 0.6f;
        }

        // compact candidate indices (index-ascending order) into LDS
        int myCnt = 0;
        #pragma unroll
        for (int j = 0; j < 32; ++j) myCnt += (v[j] >= T0);
        int pre = myCnt;
        #pragma unroll
        for (int o = 1; o < 64; o <<= 1) {
            int tu = __shfl_up(pre, o);
            if (lane >= o) pre += tu;
        }
        const int start = pre - myCnt;
        int nAll = __shfl(pre, 63);
        if (nAll > CAP) nAll = CAP;   // pathological clamp (never for this data)

        int cur = start;
        #pragma unroll
        for (int j = 0; j < 32; ++j) {
            const bool c = (v[j] >= T0);
            const int addr = (c && cur < CAP) ? cur : CAP;   // CAP = dump slot
            candIdx[wave][addr] = lane * 32 + j;
            cur += c;
        }
        asm volatile("s_waitcnt lgkmcnt(0)" ::: "memory");

        // exact fp32 recompute of candidate scores (<=2 per lane)
        float ex[2]; unsigned us[2]; int ci[2];
        #pragma unroll
        for (int p = 0; p < 2; ++p) {
            const int c = lane + 64 * p;
            const bool valid = (c < nAll);
            const int key = valid ? candIdx[wave][c] : 0;
            ci[p] = key;
            float dot = 0.f;
            const float4* kp4 = reinterpret_cast<const float4*>(Kf + (headbase + key) * DIM);
            #pragma unroll
            for (int chk = 0; chk < 16; ++chk) {
                const float4 kk = kp4[chk];
                dot = fmaf(kk.x, qlds[row][chk * 4 + 0], dot);
                dot = fmaf(kk.y, qlds[row][chk * 4 + 1], dot);
                dot = fmaf(kk.z, qlds[row][chk * 4 + 2], dot);
                dot = fmaf(kk.w, qlds[row][chk * 4 + 3], dot);
            }
            ex[p] = dot;
            unsigned u = __float_as_uint(dot);
            u ^= (unsigned)((int)u >> 31) | 0x80000000u;   // order-preserving transform
            us[p] = valid ? u : 0u;
        }

        // exact 64th-largest via 32-step bitwise ballot descent (terminates!)
        unsigned cut = 0u;
        #pragma unroll
        for (int b = 31; b >= 0; --b) {
            const unsigned trial = cut | (1u << b);
            const int cnt = __popcll(__ballot(us[0] >= trial)) +
                            __popcll(__ballot(us[1] >= trial));
            if (cnt >= TOPK) cut = trial;
        }

        // selection with lax.top_k tie-break (equal scores: lowest index first)
        const unsigned long long beq0 = __ballot(us[0] == cut);
        const unsigned long long beq1 = __ballot(us[1] == cut);
        const int cntGt = __popcll(__ballot(us[0] > cut)) + __popcll(__ballot(us[1] > cut));
        const int need  = TOPK - cntGt;
        const int rank0 = __popcll(beq0 & mlt);
        const int rank1 = __popcll(beq0) + __popcll(beq1 & mlt);
        const bool sel0 = (us[0] > cut) || ((us[0] == cut) && (rank0 < need));
        const bool sel1 = (us[1] > cut) || ((us[1] == cut) && (rank1 < need));

        // softmax over selected (exact fp32)
        float mxe = fmaxf(sel0 ? ex[0] : -1e30f, sel1 ? ex[1] : -1e30f);
        #pragma unroll
        for (int o = 32; o > 0; o >>= 1) mxe = fmaxf(mxe, __shfl_xor(mxe, o));
        const float w0 = sel0 ? expf(ex[0] - mxe) : 0.f;
        const float w1 = sel1 ? expf(ex[1] - mxe) : 0.f;
        float zs = w0 + w1;
        #pragma unroll
        for (int o = 32; o > 0; o >>= 1) zs += __shfl_xor(zs, o);
        const float inv = 1.f / zs;

        // compact selected (key, weight) pairs
        pvK[wave][lane] = 0;          // defensive init (poisoned LDS)
        pvW[wave][lane] = 0.f;
        const unsigned long long bs0 = __ballot(sel0);
        const unsigned long long bs1 = __ballot(sel1);
        const int pos0 = __popcll(bs0 & mlt);
        const int pos1 = __popcll(bs0) + __popcll(bs1 & mlt);
        if (sel0) { pvK[wave][pos0] = ci[0]; pvW[wave][pos0] = w0 * inv; }
        if (sel1) { pvK[wave][pos1] = ci[1]; pvW[wave][pos1] = w1 * inv; }
        asm volatile("s_waitcnt lgkmcnt(0)" ::: "memory");

        // PV: lane = d, gather 64 V rows (coalesced 256B per row)
        float acc = 0.f;
        #pragma unroll 16
        for (int i = 0; i < TOPK; ++i) {
            const int   ki = pvK[wave][i];
            const float wi = pvW[wave][i];
            acc = fmaf(wi, Vf[(headbase + ki) * DIM + lane], acc);
        }
        Out[(rowbase + row) * DIM + lane] = acc;
    }
}

extern "C" void kernel_launch(void* const* d_in, const int* in_sizes, int n_in,
                              void* d_out, int out_size, void* d_ws, size_t ws_size,
                              hipStream_t stream)
{
    const float* Q = (const float*)d_in[0];
    const float* K = (const float*)d_in[1];
    const float* V = (const float*)d_in[2];
    float* Out = (float*)d_out;

    const int nElem = 2 * 16 * 2048 * 64;   // 4194304 per tensor
    const size_t needWs = (size_t)2 * (size_t)nElem * sizeof(_Float16);

    if (ws_size >= needWs) {
        _Float16* Q16 = (_Float16*)d_ws;
        _Float16* K16 = Q16 + nElem;
        cvt_f16_kernel<<<(nElem / 4) / 256, 256, 0, stream>>>(Q, K, Q16, K16, nElem / 4);
        topk_attn_kernel<true><<<NROWTOT / ROWS, 512, 0, stream>>>(Q, K, V, Q16, K16, Out);
    } else {
        topk_attn_kernel<false><<<NROWTOT / ROWS, 512, 0, stream>>>(Q, K, V, nullptr, nullptr, Out);
    }
}